// Round 4
// baseline (56.995 us; speedup 1.0000x reference)
//
#include <hip/hip_runtime.h>
#include <math.h>

// Poincare-ball KG scoring (MuRP-style) for MI355X, v4.
// The kernel is bound by the random-gather L2-miss path (~2.6 TB/s measured).
// Fix: compact Eh (51MB f32) to bf16 (25.6MB) in d_ws each call, halving
// miss-path bytes. rvh/W (256KB each) stay f32 (L2-hot).

#define EPSF 1e-5f
#define MAXN (1.0f - 1e-5f)

__device__ __forceinline__ float dot4(const float4 a, const float4 b) {
    return a.x * b.x + a.y * b.y + a.z * b.z + a.w * b.w;
}

// pack two f32 (bit patterns lo,hi) into one u32 of two bf16, RTNE
__device__ __forceinline__ unsigned bfpack(unsigned lo, unsigned hi) {
    unsigned bl = (lo + 0x7FFFu + ((lo >> 16) & 1u)) >> 16;
    unsigned bh = (hi + 0x7FFFu + ((hi >> 16) & 1u)) & 0xFFFF0000u;
    return (bl & 0xFFFFu) | bh;
}

// Eh f32 -> bf16: 8 elems/thread, 32B read, 16B write
__global__ __launch_bounds__(256) void cvt_bf16_kernel(
    const uint4* __restrict__ src, uint4* __restrict__ dst, int ngroups)
{
    int i = blockIdx.x * 256 + threadIdx.x;
    if (i >= ngroups) return;
    uint4 a = src[2 * i];
    uint4 b = src[2 * i + 1];
    uint4 o;
    o.x = bfpack(a.x, a.y);
    o.y = bfpack(a.z, a.w);
    o.z = bfpack(b.x, b.y);
    o.w = bfpack(b.z, b.w);
    dst[i] = o;
}

__device__ __forceinline__ float bflo(unsigned u) { return __uint_as_float(u << 16); }
__device__ __forceinline__ float bfhi(unsigned u) { return __uint_as_float(u & 0xFFFF0000u); }

// 4 lanes per element. h,t from bf16 rows (256B = 4 uint4/lane-set);
// r,w from f32 rows (L2-hot). One pass -> 7 dot products -> scalar finish.
__global__ __launch_bounds__(256) void poincare_score_bf16_kernel(
    const uint4* __restrict__ Ehb, const float* __restrict__ rvh,
    const float* __restrict__ W, const float* __restrict__ bias0,
    const float* __restrict__ bias1, const int* __restrict__ head_idx,
    const int* __restrict__ rel_idx, const int* __restrict__ tail_idx,
    float* __restrict__ out, int total)
{
    const int tid   = threadIdx.x;
    const int lane4 = tid & 3;
    const int e     = blockIdx.x * 64 + (tid >> 2);
    if (e >= total) return;

    const int hi = head_idx[e];
    const int ri = rel_idx[e];
    const int ti = tail_idx[e];

    const float4* __restrict__ rvh4 = reinterpret_cast<const float4*>(rvh);
    const float4* __restrict__ W4   = reinterpret_cast<const float4*>(W);

    // bf16 row = 128 bf16 = 256B = 16 uint4
    const uint4* __restrict__ hrow = Ehb + (size_t)hi * 16 + lane4;
    const uint4* __restrict__ trow = Ehb + (size_t)ti * 16 + lane4;
    const float4* __restrict__ rrow = rvh4 + (size_t)ri * 32 + lane4 * 2;
    const float4* __restrict__ wrow = W4   + (size_t)ri * 32 + lane4 * 2;

    float H2 = 0.f, T2 = 0.f, R2 = 0.f, TR = 0.f;
    float HW2 = 0.f, HWT = 0.f, HWR = 0.f;

#pragma unroll
    for (int j = 0; j < 4; ++j) {
        // h,t chunk j: dims [lane4*8 + j*32, +8)
        uint4 hq = hrow[j * 4];
        uint4 tq = trow[j * 4];
        // matching r,w dims: two consecutive float4 at float4-index lane4*2 + j*8
        float4 r0 = rrow[j * 8],     r1 = rrow[j * 8 + 1];
        float4 w0 = wrow[j * 8],     w1 = wrow[j * 8 + 1];

        float h0 = bflo(hq.x), h1 = bfhi(hq.x), h2_ = bflo(hq.y), h3 = bfhi(hq.y);
        float h4 = bflo(hq.z), h5 = bfhi(hq.z), h6 = bflo(hq.w), h7 = bfhi(hq.w);
        float t0 = bflo(tq.x), t1 = bfhi(tq.x), t2_ = bflo(tq.y), t3 = bfhi(tq.y);
        float t4 = bflo(tq.z), t5 = bfhi(tq.z), t6 = bflo(tq.w), t7 = bfhi(tq.w);

        float4 ha = make_float4(h0, h1, h2_, h3);
        float4 hb = make_float4(h4, h5, h6, h7);
        float4 ta = make_float4(t0, t1, t2_, t3);
        float4 tb = make_float4(t4, t5, t6, t7);

        float4 hwa, hwb;
        hwa.x = ha.x * w0.x; hwa.y = ha.y * w0.y; hwa.z = ha.z * w0.z; hwa.w = ha.w * w0.w;
        hwb.x = hb.x * w1.x; hwb.y = hb.y * w1.y; hwb.z = hb.z * w1.z; hwb.w = hb.w * w1.w;

        H2  += dot4(ha, ha)  + dot4(hb, hb);
        T2  += dot4(ta, ta)  + dot4(tb, tb);
        R2  += dot4(r0, r0)  + dot4(r1, r1);
        TR  += dot4(ta, r0)  + dot4(tb, r1);
        HW2 += dot4(hwa, hwa) + dot4(hwb, hwb);
        HWT += dot4(hwa, ta) + dot4(hwb, tb);
        HWR += dot4(hwa, r0) + dot4(hwb, r1);
    }

    // one batched reduction round across the 4 lanes (2 steps)
#pragma unroll
    for (int m = 1; m <= 2; m <<= 1) {
        H2  += __shfl_xor(H2,  m);
        T2  += __shfl_xor(T2,  m);
        R2  += __shfl_xor(R2,  m);
        TR  += __shfl_xor(TR,  m);
        HW2 += __shfl_xor(HW2, m);
        HWT += __shfl_xor(HWT, m);
        HWR += __shfl_xor(HWR, m);
    }

    // ---- scalar finish ----
    float nh = sqrtf(H2 + 1e-15f);
    float sh = (nh > MAXN) ? (MAXN / nh) : 1.0f;
    float h2 = H2 * sh * sh;

    float nt = sqrtf(T2 + 1e-15f);
    float st = (nt > MAXN) ? (MAXN / nt) : 1.0f;
    float t2 = T2 * st * st;

    float nr = sqrtf(R2 + 1e-15f);
    float sr = (nr > MAXN) ? (MAXN / nr) : 1.0f;
    float r2 = R2 * sr * sr;

    float xy = TR * st * sr;

    float nl = sqrtf(h2 + 1e-15f);
    nl = fminf(fmaxf(nl, EPSF), MAXN);
    float lf = 0.5f * logf((1.0f + nl) / (1.0f - nl)) / nl;   // artanh(nl)/nl
    float a0 = lf * sh;
    float v2 = a0 * a0 * HW2;

    float nv = fmaxf(sqrtf(v2 + 1e-15f), EPSF);
    float ef = tanhf(nv) / nv;
    float b0 = ef * a0;
    float hd2 = b0 * b0 * HW2;

    float nhd = sqrtf(hd2 + 1e-15f);
    float shd = (nhd > MAXN) ? (MAXN / nhd) : 1.0f;
    float b = b0 * shd;
    hd2 = b * b * HW2;

    float ct  = 1.0f + 2.0f * xy + r2;
    float cr  = 1.0f - t2;
    float den = fmaxf(1.0f + 2.0f * xy + t2 * r2, EPSF);
    float id  = 1.0f / den;
    float p = id * ct * st;
    float q = id * cr * sr;
    float tl2 = p * p * T2 + 2.0f * p * q * TR + q * q * R2;

    float ntl = sqrtf(tl2 + 1e-15f);
    float stl = (ntl > MAXN) ? (MAXN / ntl) : 1.0f;
    p *= stl; q *= stl;
    tl2 = tl2 * stl * stl;

    float hdtl = b * (p * HWT + q * HWR);
    float d2   = hd2 + tl2 - 2.0f * hdtl;
    float dn   = fmaxf((1.0f - hd2) * (1.0f - tl2), EPSF);
    float arg  = fmaxf(1.0f + 2.0f * d2 / dn, 1.0f + 1e-7f);
    float dist = acoshf(arg);

    if (lane4 == 0) {
        out[e] = bias0[hi] + bias1[ti] - dist;
    }
}

// f32 fallback (v3 path) if ws too small for the bf16 copy of Eh
__global__ __launch_bounds__(256) void poincare_score_f32_kernel(
    const float* __restrict__ Eh, const float* __restrict__ rvh,
    const float* __restrict__ W, const float* __restrict__ bias0,
    const float* __restrict__ bias1, const int* __restrict__ head_idx,
    const int* __restrict__ rel_idx, const int* __restrict__ tail_idx,
    float* __restrict__ out, int total)
{
    const int tid   = threadIdx.x;
    const int lane4 = tid & 3;
    const int e     = blockIdx.x * 64 + (tid >> 2);
    if (e >= total) return;

    const int hi = head_idx[e];
    const int ri = rel_idx[e];
    const int ti = tail_idx[e];

    const float4* __restrict__ Eh4  = reinterpret_cast<const float4*>(Eh);
    const float4* __restrict__ rvh4 = reinterpret_cast<const float4*>(rvh);
    const float4* __restrict__ W4   = reinterpret_cast<const float4*>(W);

    const float4* __restrict__ hrow = Eh4  + (size_t)hi * 32 + lane4;
    const float4* __restrict__ trow = Eh4  + (size_t)ti * 32 + lane4;
    const float4* __restrict__ rrow = rvh4 + (size_t)ri * 32 + lane4;
    const float4* __restrict__ wrow = W4   + (size_t)ri * 32 + lane4;

    float H2 = 0.f, T2 = 0.f, R2 = 0.f, TR = 0.f;
    float HW2 = 0.f, HWT = 0.f, HWR = 0.f;
#pragma unroll
    for (int j = 0; j < 8; ++j) {
        float4 h = hrow[j * 4];
        float4 t = trow[j * 4];
        float4 r = rrow[j * 4];
        float4 w = wrow[j * 4];
        float4 hw;
        hw.x = h.x * w.x; hw.y = h.y * w.y; hw.z = h.z * w.z; hw.w = h.w * w.w;
        H2  += dot4(h, h);
        T2  += dot4(t, t);
        R2  += dot4(r, r);
        TR  += dot4(t, r);
        HW2 += dot4(hw, hw);
        HWT += dot4(hw, t);
        HWR += dot4(hw, r);
    }
#pragma unroll
    for (int m = 1; m <= 2; m <<= 1) {
        H2  += __shfl_xor(H2,  m);
        T2  += __shfl_xor(T2,  m);
        R2  += __shfl_xor(R2,  m);
        TR  += __shfl_xor(TR,  m);
        HW2 += __shfl_xor(HW2, m);
        HWT += __shfl_xor(HWT, m);
        HWR += __shfl_xor(HWR, m);
    }

    float nh = sqrtf(H2 + 1e-15f);
    float sh = (nh > MAXN) ? (MAXN / nh) : 1.0f;
    float h2 = H2 * sh * sh;
    float nt = sqrtf(T2 + 1e-15f);
    float st = (nt > MAXN) ? (MAXN / nt) : 1.0f;
    float t2 = T2 * st * st;
    float nr = sqrtf(R2 + 1e-15f);
    float sr = (nr > MAXN) ? (MAXN / nr) : 1.0f;
    float r2 = R2 * sr * sr;
    float xy = TR * st * sr;

    float nl = sqrtf(h2 + 1e-15f);
    nl = fminf(fmaxf(nl, EPSF), MAXN);
    float lf = 0.5f * logf((1.0f + nl) / (1.0f - nl)) / nl;
    float a0 = lf * sh;
    float v2 = a0 * a0 * HW2;
    float nv = fmaxf(sqrtf(v2 + 1e-15f), EPSF);
    float ef = tanhf(nv) / nv;
    float b0 = ef * a0;
    float hd2 = b0 * b0 * HW2;
    float nhd = sqrtf(hd2 + 1e-15f);
    float shd = (nhd > MAXN) ? (MAXN / nhd) : 1.0f;
    float b = b0 * shd;
    hd2 = b * b * HW2;

    float ct  = 1.0f + 2.0f * xy + r2;
    float cr  = 1.0f - t2;
    float den = fmaxf(1.0f + 2.0f * xy + t2 * r2, EPSF);
    float id  = 1.0f / den;
    float p = id * ct * st;
    float q = id * cr * sr;
    float tl2 = p * p * T2 + 2.0f * p * q * TR + q * q * R2;
    float ntl = sqrtf(tl2 + 1e-15f);
    float stl = (ntl > MAXN) ? (MAXN / ntl) : 1.0f;
    p *= stl; q *= stl;
    tl2 = tl2 * stl * stl;

    float hdtl = b * (p * HWT + q * HWR);
    float d2   = hd2 + tl2 - 2.0f * hdtl;
    float dn   = fmaxf((1.0f - hd2) * (1.0f - tl2), EPSF);
    float arg  = fmaxf(1.0f + 2.0f * d2 / dn, 1.0f + 1e-7f);
    float dist = acoshf(arg);

    if (lane4 == 0) {
        out[e] = bias0[hi] + bias1[ti] - dist;
    }
}

extern "C" void kernel_launch(void* const* d_in, const int* in_sizes, int n_in,
                              void* d_out, int out_size, void* d_ws, size_t ws_size,
                              hipStream_t stream) {
    const float* Eh       = (const float*)d_in[0];
    const float* rvh      = (const float*)d_in[1];
    const float* W        = (const float*)d_in[2];
    const float* bias0    = (const float*)d_in[3];
    const float* bias1    = (const float*)d_in[4];
    const int*   head_idx = (const int*)d_in[5];
    const int*   rel_idx  = (const int*)d_in[6];
    const int*   tail_idx = (const int*)d_in[7];
    float* out = (float*)d_out;

    const int total  = in_sizes[5];            // B*K = 262144
    const int blocks = (total + 63) / 64;      // 64 elements / 256-thr block

    const int n_eh = in_sizes[0];              // N_ENT * DIM = 12,800,000
    const size_t need = (size_t)n_eh * 2;      // bf16 bytes

    if (ws_size >= need && (n_eh & 7) == 0) {
        // 1) compact Eh -> bf16 in d_ws (every call; deterministic)
        const int ngroups = n_eh / 8;
        const int cblocks = (ngroups + 255) / 256;
        cvt_bf16_kernel<<<cblocks, 256, 0, stream>>>(
            (const uint4*)Eh, (uint4*)d_ws, ngroups);
        // 2) score from bf16 Eh
        poincare_score_bf16_kernel<<<blocks, 256, 0, stream>>>(
            (const uint4*)d_ws, rvh, W, bias0, bias1,
            head_idx, rel_idx, tail_idx, out, total);
    } else {
        poincare_score_f32_kernel<<<blocks, 256, 0, stream>>>(
            Eh, rvh, W, bias0, bias1, head_idx, rel_idx, tail_idx, out, total);
    }
}

// Round 5
// 50.767 us; speedup vs baseline: 1.1227x; 1.1227x over previous
//
#include <hip/hip_runtime.h>
#include <math.h>

// Poincare-ball KG scoring (MuRP-style) for MI355X, v5.
// Diagnosis R4: latency-bound gather (time constant while bytes halved).
// Fix: h/t row gathers via global_load_lds (async, VGPR-free) -> all 8 gather
// instructions per wave in flight behind ONE vmcnt(0); 20 waves/CU via 32KiB
// LDS blocks. Eh compacted to bf16 in d_ws (halves gather bytes + LDS).

#define EPSF 1e-5f
#define MAXN (1.0f - 1e-5f)

__device__ __forceinline__ float dot4(const float4 a, const float4 b) {
    return a.x * b.x + a.y * b.y + a.z * b.z + a.w * b.w;
}

// pack two f32 (bit patterns lo,hi) into one u32 of two bf16, RTNE
__device__ __forceinline__ unsigned bfpack(unsigned lo, unsigned hi) {
    unsigned bl = (lo + 0x7FFFu + ((lo >> 16) & 1u)) >> 16;
    unsigned bh = (hi + 0x7FFFu + ((hi >> 16) & 1u)) & 0xFFFF0000u;
    return (bl & 0xFFFFu) | bh;
}

// Eh f32 -> bf16: 8 elems/thread
__global__ __launch_bounds__(256) void cvt_bf16_kernel(
    const uint4* __restrict__ src, uint4* __restrict__ dst, int ngroups)
{
    int i = blockIdx.x * 256 + threadIdx.x;
    if (i >= ngroups) return;
    uint4 a = src[2 * i];
    uint4 b = src[2 * i + 1];
    uint4 o;
    o.x = bfpack(a.x, a.y);
    o.y = bfpack(a.z, a.w);
    o.z = bfpack(b.x, b.y);
    o.w = bfpack(b.z, b.w);
    dst[i] = o;
}

__device__ __forceinline__ float bflo(unsigned u) { return __uint_as_float(u << 16); }
__device__ __forceinline__ float bfhi(unsigned u) { return __uint_as_float(u & 0xFFFF0000u); }

// async global->LDS, 16B per lane; per-lane global address, wave-uniform LDS base
__device__ __forceinline__ void gload_lds16(const void* g, void* l) {
    typedef const __attribute__((address_space(1))) unsigned int GU;
    typedef __attribute__((address_space(3))) unsigned int LU;
    __builtin_amdgcn_global_load_lds((GU*)g, (LU*)l, 16, 0, 0);
}

// 4 lanes per element, 16 elements per wave, 4 waves per block.
// LDS per wave: h rows [0..256) uint4, t rows [256..512).
// Layout: element j (lane=j*4+sub), row quarter k at uint4 index k*64 + j*4 + sub.
__global__ __launch_bounds__(256) void poincare_score_lds_kernel(
    const char* __restrict__ Ehb, const float* __restrict__ rvh,
    const float* __restrict__ W, const float* __restrict__ bias0,
    const float* __restrict__ bias1, const int* __restrict__ head_idx,
    const int* __restrict__ rel_idx, const int* __restrict__ tail_idx,
    float* __restrict__ out, int total)
{
    __shared__ uint4 lds[4][512];          // 32 KiB/block -> 5 blocks/CU

    const int lane  = threadIdx.x & 63;
    const int wave  = threadIdx.x >> 6;
    const int sub   = lane & 3;
    const int e     = blockIdx.x * 64 + wave * 16 + (lane >> 2);
    const int ec    = (e < total) ? e : (total - 1);   // keep all lanes active

    const int hi = head_idx[ec];
    const int ri = rel_idx[ec];
    const int ti = tail_idx[ec];

    uint4* __restrict__ ldsw = lds[wave];

    // per-lane global source: row base + sub*16B; quarter k adds k*64B
    const char* hg = Ehb + ((size_t)(unsigned)hi << 8) + (sub << 4);
    const char* tg = Ehb + ((size_t)(unsigned)ti << 8) + (sub << 4);

    // issue ALL 8 gather instructions (async, no VGPR destinations)
#pragma unroll
    for (int k = 0; k < 4; ++k)
        gload_lds16(hg + k * 64, (void*)(ldsw + k * 64));
#pragma unroll
    for (int k = 0; k < 4; ++k)
        gload_lds16(tg + k * 64, (void*)(ldsw + 256 + k * 64));

    const float4* __restrict__ rrow =
        reinterpret_cast<const float4*>(rvh) + (size_t)ri * 32 + sub * 2;
    const float4* __restrict__ wrow =
        reinterpret_cast<const float4*>(W)   + (size_t)ri * 32 + sub * 2;

    // one wait for the whole gather burst (per-wave vmcnt; no barrier needed)
    asm volatile("s_waitcnt vmcnt(0)" ::: "memory");
    __builtin_amdgcn_sched_barrier(0);

    float H2 = 0.f, T2 = 0.f, R2 = 0.f, TR = 0.f;
    float HW2 = 0.f, HWT = 0.f, HWR = 0.f;

#pragma unroll
    for (int k = 0; k < 4; ++k) {
        uint4 hq = ldsw[k * 64 + lane];          // ds_read_b128, linear, no conflicts
        uint4 tq = ldsw[256 + k * 64 + lane];
        float4 r0 = rrow[k * 8], r1 = rrow[k * 8 + 1];   // L2-hot
        float4 w0 = wrow[k * 8], w1 = wrow[k * 8 + 1];

        float4 ha = make_float4(bflo(hq.x), bfhi(hq.x), bflo(hq.y), bfhi(hq.y));
        float4 hb = make_float4(bflo(hq.z), bfhi(hq.z), bflo(hq.w), bfhi(hq.w));
        float4 ta = make_float4(bflo(tq.x), bfhi(tq.x), bflo(tq.y), bfhi(tq.y));
        float4 tb = make_float4(bflo(tq.z), bfhi(tq.z), bflo(tq.w), bfhi(tq.w));

        float4 hwa, hwb;
        hwa.x = ha.x * w0.x; hwa.y = ha.y * w0.y; hwa.z = ha.z * w0.z; hwa.w = ha.w * w0.w;
        hwb.x = hb.x * w1.x; hwb.y = hb.y * w1.y; hwb.z = hb.z * w1.z; hwb.w = hb.w * w1.w;

        H2  += dot4(ha, ha)   + dot4(hb, hb);
        T2  += dot4(ta, ta)   + dot4(tb, tb);
        R2  += dot4(r0, r0)   + dot4(r1, r1);
        TR  += dot4(ta, r0)   + dot4(tb, r1);
        HW2 += dot4(hwa, hwa) + dot4(hwb, hwb);
        HWT += dot4(hwa, ta)  + dot4(hwb, tb);
        HWR += dot4(hwa, r0)  + dot4(hwb, r1);
    }

    // one batched reduction round across the 4 lanes (2 steps)
#pragma unroll
    for (int m = 1; m <= 2; m <<= 1) {
        H2  += __shfl_xor(H2,  m);
        T2  += __shfl_xor(T2,  m);
        R2  += __shfl_xor(R2,  m);
        TR  += __shfl_xor(TR,  m);
        HW2 += __shfl_xor(HW2, m);
        HWT += __shfl_xor(HWT, m);
        HWR += __shfl_xor(HWR, m);
    }

    // ---- scalar finish ----
    float nh = sqrtf(H2 + 1e-15f);
    float sh = (nh > MAXN) ? (MAXN / nh) : 1.0f;
    float h2 = H2 * sh * sh;

    float nt = sqrtf(T2 + 1e-15f);
    float st = (nt > MAXN) ? (MAXN / nt) : 1.0f;
    float t2 = T2 * st * st;

    float nr = sqrtf(R2 + 1e-15f);
    float sr = (nr > MAXN) ? (MAXN / nr) : 1.0f;
    float r2 = R2 * sr * sr;

    float xy = TR * st * sr;

    float nl = sqrtf(h2 + 1e-15f);
    nl = fminf(fmaxf(nl, EPSF), MAXN);
    float lf = 0.5f * logf((1.0f + nl) / (1.0f - nl)) / nl;   // artanh(nl)/nl
    float a0 = lf * sh;
    float v2 = a0 * a0 * HW2;

    float nv = fmaxf(sqrtf(v2 + 1e-15f), EPSF);
    float ef = tanhf(nv) / nv;
    float b0 = ef * a0;
    float hd2 = b0 * b0 * HW2;

    float nhd = sqrtf(hd2 + 1e-15f);
    float shd = (nhd > MAXN) ? (MAXN / nhd) : 1.0f;
    float b = b0 * shd;
    hd2 = b * b * HW2;

    float ct  = 1.0f + 2.0f * xy + r2;
    float cr  = 1.0f - t2;
    float den = fmaxf(1.0f + 2.0f * xy + t2 * r2, EPSF);
    float id  = 1.0f / den;
    float p = id * ct * st;
    float q = id * cr * sr;
    float tl2 = p * p * T2 + 2.0f * p * q * TR + q * q * R2;

    float ntl = sqrtf(tl2 + 1e-15f);
    float stl = (ntl > MAXN) ? (MAXN / ntl) : 1.0f;
    p *= stl; q *= stl;
    tl2 = tl2 * stl * stl;

    float hdtl = b * (p * HWT + q * HWR);
    float d2   = hd2 + tl2 - 2.0f * hdtl;
    float dn   = fmaxf((1.0f - hd2) * (1.0f - tl2), EPSF);
    float arg  = fmaxf(1.0f + 2.0f * d2 / dn, 1.0f + 1e-7f);
    float dist = acoshf(arg);

    if (sub == 0 && e < total) {
        out[e] = bias0[hi] + bias1[ti] - dist;
    }
}

// f32 fallback (v3 path) if ws too small for the bf16 copy of Eh
__global__ __launch_bounds__(256) void poincare_score_f32_kernel(
    const float* __restrict__ Eh, const float* __restrict__ rvh,
    const float* __restrict__ W, const float* __restrict__ bias0,
    const float* __restrict__ bias1, const int* __restrict__ head_idx,
    const int* __restrict__ rel_idx, const int* __restrict__ tail_idx,
    float* __restrict__ out, int total)
{
    const int tid   = threadIdx.x;
    const int lane4 = tid & 3;
    const int e     = blockIdx.x * 64 + (tid >> 2);
    if (e >= total) return;

    const int hi = head_idx[e];
    const int ri = rel_idx[e];
    const int ti = tail_idx[e];

    const float4* __restrict__ Eh4  = reinterpret_cast<const float4*>(Eh);
    const float4* __restrict__ rvh4 = reinterpret_cast<const float4*>(rvh);
    const float4* __restrict__ W4   = reinterpret_cast<const float4*>(W);

    const float4* __restrict__ hrow = Eh4  + (size_t)hi * 32 + lane4;
    const float4* __restrict__ trow = Eh4  + (size_t)ti * 32 + lane4;
    const float4* __restrict__ rrow = rvh4 + (size_t)ri * 32 + lane4;
    const float4* __restrict__ wrow = W4   + (size_t)ri * 32 + lane4;

    float H2 = 0.f, T2 = 0.f, R2 = 0.f, TR = 0.f;
    float HW2 = 0.f, HWT = 0.f, HWR = 0.f;
#pragma unroll
    for (int j = 0; j < 8; ++j) {
        float4 h = hrow[j * 4];
        float4 t = trow[j * 4];
        float4 r = rrow[j * 4];
        float4 w = wrow[j * 4];
        float4 hw;
        hw.x = h.x * w.x; hw.y = h.y * w.y; hw.z = h.z * w.z; hw.w = h.w * w.w;
        H2  += dot4(h, h);
        T2  += dot4(t, t);
        R2  += dot4(r, r);
        TR  += dot4(t, r);
        HW2 += dot4(hw, hw);
        HWT += dot4(hw, t);
        HWR += dot4(hw, r);
    }
#pragma unroll
    for (int m = 1; m <= 2; m <<= 1) {
        H2  += __shfl_xor(H2,  m);
        T2  += __shfl_xor(T2,  m);
        R2  += __shfl_xor(R2,  m);
        TR  += __shfl_xor(TR,  m);
        HW2 += __shfl_xor(HW2, m);
        HWT += __shfl_xor(HWT, m);
        HWR += __shfl_xor(HWR, m);
    }

    float nh = sqrtf(H2 + 1e-15f);
    float sh = (nh > MAXN) ? (MAXN / nh) : 1.0f;
    float h2 = H2 * sh * sh;
    float nt = sqrtf(T2 + 1e-15f);
    float st = (nt > MAXN) ? (MAXN / nt) : 1.0f;
    float t2 = T2 * st * st;
    float nr = sqrtf(R2 + 1e-15f);
    float sr = (nr > MAXN) ? (MAXN / nr) : 1.0f;
    float r2 = R2 * sr * sr;
    float xy = TR * st * sr;

    float nl = sqrtf(h2 + 1e-15f);
    nl = fminf(fmaxf(nl, EPSF), MAXN);
    float lf = 0.5f * logf((1.0f + nl) / (1.0f - nl)) / nl;
    float a0 = lf * sh;
    float v2 = a0 * a0 * HW2;
    float nv = fmaxf(sqrtf(v2 + 1e-15f), EPSF);
    float ef = tanhf(nv) / nv;
    float b0 = ef * a0;
    float hd2 = b0 * b0 * HW2;
    float nhd = sqrtf(hd2 + 1e-15f);
    float shd = (nhd > MAXN) ? (MAXN / nhd) : 1.0f;
    float b = b0 * shd;
    hd2 = b * b * HW2;

    float ct  = 1.0f + 2.0f * xy + r2;
    float cr  = 1.0f - t2;
    float den = fmaxf(1.0f + 2.0f * xy + t2 * r2, EPSF);
    float id  = 1.0f / den;
    float p = id * ct * st;
    float q = id * cr * sr;
    float tl2 = p * p * T2 + 2.0f * p * q * TR + q * q * R2;
    float ntl = sqrtf(tl2 + 1e-15f);
    float stl = (ntl > MAXN) ? (MAXN / ntl) : 1.0f;
    p *= stl; q *= stl;
    tl2 = tl2 * stl * stl;

    float hdtl = b * (p * HWT + q * HWR);
    float d2   = hd2 + tl2 - 2.0f * hdtl;
    float dn   = fmaxf((1.0f - hd2) * (1.0f - tl2), EPSF);
    float arg  = fmaxf(1.0f + 2.0f * d2 / dn, 1.0f + 1e-7f);
    float dist = acoshf(arg);

    if (lane4 == 0) {
        out[e] = bias0[hi] + bias1[ti] - dist;
    }
}

extern "C" void kernel_launch(void* const* d_in, const int* in_sizes, int n_in,
                              void* d_out, int out_size, void* d_ws, size_t ws_size,
                              hipStream_t stream) {
    const float* Eh       = (const float*)d_in[0];
    const float* rvh      = (const float*)d_in[1];
    const float* W        = (const float*)d_in[2];
    const float* bias0    = (const float*)d_in[3];
    const float* bias1    = (const float*)d_in[4];
    const int*   head_idx = (const int*)d_in[5];
    const int*   rel_idx  = (const int*)d_in[6];
    const int*   tail_idx = (const int*)d_in[7];
    float* out = (float*)d_out;

    const int total  = in_sizes[5];            // B*K = 262144
    const int blocks = (total + 63) / 64;      // 64 elements / 256-thr block

    const int n_eh = in_sizes[0];              // N_ENT * DIM = 12,800,000
    const size_t need = (size_t)n_eh * 2;      // bf16 bytes

    if (ws_size >= need && (n_eh & 7) == 0) {
        const int ngroups = n_eh / 8;
        const int cblocks = (ngroups + 255) / 256;
        cvt_bf16_kernel<<<cblocks, 256, 0, stream>>>(
            (const uint4*)Eh, (uint4*)d_ws, ngroups);
        poincare_score_lds_kernel<<<blocks, 256, 0, stream>>>(
            (const char*)d_ws, rvh, W, bias0, bias1,
            head_idx, rel_idx, tail_idx, out, total);
    } else {
        poincare_score_f32_kernel<<<blocks, 256, 0, stream>>>(
            Eh, rvh, W, bias0, bias1, head_idx, rel_idx, tail_idx, out, total);
    }
}